// Round 15
// baseline (1793.542 us; speedup 1.0000x reference)
//
#include <hip/hip_runtime.h>
#include <hip/hip_bf16.h>

#define B_ 512
#define T_ 128
#define DIN_ 256
#define H_ 512
#define KP_ 520             // LDS stride (bf16) K=512 weights
#define KP0_ 264            // LDS stride K=256 (wih0)
#define OUT_MAIN ((size_t)B_ * T_ * H_)
#define GISLAB 12288
#define NFLG 196608

typedef __attribute__((ext_vector_type(8))) short short8;
typedef __attribute__((ext_vector_type(4))) float f32x4;

__device__ __forceinline__ float sigm(float v) { return 1.0f / (1.0f + __expf(-v)); }

__device__ __forceinline__ unsigned short f2bf(float f) {
    union { __hip_bfloat16 b; unsigned short u; } c;
    c.b = __float2bfloat16(f);
    return c.u;
}

__device__ __forceinline__ short8 cvt8v(f32x4 u, f32x4 v) {
    short8 o;
    o[0] = (short)f2bf(u[0]); o[1] = (short)f2bf(u[1]);
    o[2] = (short)f2bf(u[2]); o[3] = (short)f2bf(u[3]);
    o[4] = (short)f2bf(v[0]); o[5] = (short)f2bf(v[1]);
    o[6] = (short)f2bf(v[2]); o[7] = (short)f2bf(v[3]);
    return o;
}

// coherent-point 16B load (sc0 sc1) — empirically the fastest correct transport
// (R12 1353 vs R13/R14 L2-allocating 1998/1790).
__device__ __forceinline__ short8 ldh(const __hip_bfloat16* p) {
    short8 r;
    asm volatile("global_load_dwordx4 %0, %1, off sc0 sc1" : "=v"(r) : "v"(p));
    return r;
}
#define VMWAIT(N) do { asm volatile("s_waitcnt vmcnt(" #N ")" ::: "memory"); \
                       __builtin_amdgcn_sched_barrier(0); } while (0)

__device__ __forceinline__ unsigned long long load_sc8(const __hip_bfloat16* p) {
    return __hip_atomic_load((const unsigned long long*)p, __ATOMIC_RELAXED, __HIP_MEMORY_SCOPE_AGENT);
}
__device__ __forceinline__ void store_sc8u(__hip_bfloat16* p, unsigned long long v) {
    __hip_atomic_store((unsigned long long*)p, v, __ATOMIC_RELAXED, __HIP_MEMORY_SCOPE_AGENT);
}
__device__ __forceinline__ void store_sc8(__hip_bfloat16* p, f32x4 h4) {
    union { unsigned short s[4]; unsigned long long u; } r;
    r.s[0] = f2bf(h4[0]); r.s[1] = f2bf(h4[1]);
    r.s[2] = f2bf(h4[2]); r.s[3] = f2bf(h4[3]);
    store_sc8u(p, r.u);
}

__device__ __forceinline__ f32x4 unpk(unsigned long long u) {
    f32x4 r;
    r[0] = __uint_as_float((unsigned)(u & 0xffffull) << 16);
    r[1] = __uint_as_float((unsigned)((u >> 16) & 0xffffull) << 16);
    r[2] = __uint_as_float((unsigned)((u >> 32) & 0xffffull) << 16);
    r[3] = __uint_as_float((unsigned)((u >> 48) & 0xffffull) << 16);
    return r;
}

__device__ __forceinline__ void pollw(const int* p) {
    if (p)
        while (__hip_atomic_load(p, __ATOMIC_RELAXED, __HIP_MEMORY_SCOPE_AGENT) == 0)
            __builtin_amdgcn_s_sleep(1);
}

#define FIDX(t, bt, jp, w) (((((t) * 4 + (bt)) * 16 + (jp)) * 8) + (w))

__global__ void init_kernel(int* __restrict__ flg)
{
    int i = blockIdx.x * blockDim.x + threadIdx.x;
    int stride = gridDim.x * blockDim.x;
    for (int k = i; k < NFLG; k += stride)
        __hip_atomic_store(&flg[k], 0, __ATOMIC_RELAXED, __HIP_MEMORY_SCOPE_AGENT);
}

// acc: 0,1 = r ; 2,3 = z ; NB,NB+1 = n
template<int KP, int NB>
__device__ __forceinline__ void chunk6(const __hip_bfloat16* wl, int l15, int kg, int kc,
                                       short8 bf, f32x4* acc) {
    #pragma unroll
    for (int g = 0; g < 3; ++g) {
        const int ai = (g == 2) ? NB : g * 2;
        #pragma unroll
        for (int jh = 0; jh < 2; ++jh) {
            short8 wf = *(const short8*)&wl[(size_t)(g * 32 + jh * 16 + l15) * KP + kc * 32 + kg];
            acc[ai + jh] = __builtin_amdgcn_mfma_f32_16x16x32_bf16(wf, bf, acc[ai + jh], 0, 0, 0);
        }
    }
}

// 16-deep pipelined gather of 16 x 1KB tiles (issue all, counted drains)
template<int NB>
__device__ __forceinline__ void gather16d(const __hip_bfloat16* tb, const __hip_bfloat16* wl,
                                          int l15, int kg, bool z, f32x4* acc)
{
    const short8 zed = {0,0,0,0,0,0,0,0};
    VMWAIT(0);   // honest vmcnt baseline
    short8 v[16];
    #pragma unroll
    for (int i = 0; i < 16; ++i) v[i] = ldh(tb + i * 512);
    VMWAIT(12);
    #pragma unroll
    for (int i = 0; i < 4; ++i)  chunk6<KP_, NB>(wl, l15, kg, i, z ? zed : v[i], acc);
    VMWAIT(8);
    #pragma unroll
    for (int i = 4; i < 8; ++i)  chunk6<KP_, NB>(wl, l15, kg, i, z ? zed : v[i], acc);
    VMWAIT(4);
    #pragma unroll
    for (int i = 8; i < 12; ++i) chunk6<KP_, NB>(wl, l15, kg, i, z ? zed : v[i], acc);
    VMWAIT(0);
    #pragma unroll
    for (int i = 12; i < 16; ++i) chunk6<KP_, NB>(wl, l15, kg, i, z ? zed : v[i], acc);
}

// 256 blocks x 512 threads. XCD-clustered decode (bid%8 heuristic, perf-only):
//   xg<4:  idx<16 -> R0(bt=xg,jp=idx); idx>=16 -> G1(bt=xg,jp=idx-16)  [XCD xg]
//   xg>=4: idx<16 -> R1(bt=xg-4,jp=idx); else exit                      [XCD xg]
// FULLT=true: h0/h1 are full-T write-once buffers -> R0 has NO backpressure wait
// (free-runs its recurrence chain); downstream stragglers never couple back.
// Transport everywhere: sc0sc1 coherent point (fastest measured). FULLT=false:
// exact R12 fallback (4-deep rings + backpressure).
template<bool FULLT>
__global__ __launch_bounds__(512) void gru_wave(
    const float* __restrict__ x, const int* __restrict__ is_init,
    const float* __restrict__ h_in,
    const float* __restrict__ wih0, const float* __restrict__ whh0,
    const float* __restrict__ bih0, const float* __restrict__ bhh0,
    const float* __restrict__ wih1, const float* __restrict__ whh1,
    const float* __restrict__ bih1, const float* __restrict__ bhh1,
    char* __restrict__ ws, float* __restrict__ out)
{
    __shared__ __hip_bfloat16 wsh[96 * KP_ + 96 * KP0_];   // 150528 B

    constexpr size_t OFFH1 = FULLT ? 67108864ull  : 2097152ull;
    constexpr size_t OFFGI = FULLT ? 134217728ull : 4194304ull;
    constexpr size_t OFFFL = FULLT ? 141557760ull : 16777216ull;

    const int bid = blockIdx.x;
    const int xg = bid & 7;
    const int idx = bid >> 3;
    int stage, bt, jp;
    if (xg < 4) { bt = xg; if (idx < 16) { stage = 0; jp = idx; } else { stage = 2; jp = idx - 16; } }
    else        { if (idx >= 16) return; stage = 1; bt = xg - 4; jp = idx; }

    __hip_bfloat16* h0r = (__hip_bfloat16*)ws;
    __hip_bfloat16* h1r = (__hip_bfloat16*)(ws + OFFH1);
    __hip_bfloat16* gi1 = (__hip_bfloat16*)(ws + OFFGI);   // always 4-deep ring
    int* flg  = (int*)(ws + OFFFL);
    int* fh0  = flg;
    int* fh1  = flg + 65536;
    int* fgi1 = flg + 131072;

    const int tid = threadIdx.x;
    const int lane = tid & 63;
    const int w = tid >> 6;
    const int l15 = lane & 15;
    const int q = lane >> 4;
    const int kg = q * 8;
    const int qr4 = q * 4;
    const int rb = bt * 128;
    const int jb = jp * 32;
    const int bw = rb + w * 16 + l15;
    const int b16 = bt * 8 + w;

    // ---- stage weights into LDS (f32 -> bf16), once ----
    __hip_bfloat16* wlds  = wsh;
    __hip_bfloat16* wlds2 = wsh + 96 * KP_;
    {
        const float* Wsrc = (stage == 0) ? whh0 : (stage == 1) ? whh1 : wih1;
        for (int ii = tid; ii < 96 * 64; ii += 512) {
            int gr = ii >> 6, c8 = ii & 63;
            int grow = (gr >> 5) * H_ + jb + (gr & 31);
            const float* p = Wsrc + (size_t)grow * H_ + c8 * 8;
            *(short8*)&wlds[(size_t)gr * KP_ + c8 * 8] = cvt8v(*(const f32x4*)p, *(const f32x4*)(p + 4));
        }
        if (stage == 0) {
            for (int ii = tid; ii < 96 * 32; ii += 512) {
                int gr = ii >> 5, c8 = ii & 31;
                int grow = (gr >> 5) * H_ + jb + (gr & 31);
                const float* p = wih0 + (size_t)grow * DIN_ + c8 * 8;
                *(short8*)&wlds2[(size_t)gr * KP0_ + c8 * 8] = cvt8v(*(const f32x4*)p, *(const f32x4*)(p + 4));
            }
        }
    }

    // ---- per-lane constants for R stages ----
    f32x4 bR[2], bZ[2], bIN[2], bHN[2], hp[2];
    if (stage < 2) {
        const float* bi = stage ? bih1 : bih0;
        const float* bh = stage ? bhh1 : bhh0;
        #pragma unroll
        for (int jh = 0; jh < 2; ++jh) {
            const int j4 = jb + jh * 16 + qr4;
            bR[jh]  = *(const f32x4*)&bi[j4]          + *(const f32x4*)&bh[j4];
            bZ[jh]  = *(const f32x4*)&bi[H_ + j4]     + *(const f32x4*)&bh[H_ + j4];
            bIN[jh] = *(const f32x4*)&bi[2 * H_ + j4];
            bHN[jh] = *(const f32x4*)&bh[2 * H_ + j4];
            hp[jh]  = *(const f32x4*)&h_in[(size_t)bw * 2 * H_ + (size_t)stage * H_ + j4];
        }
    }
    __syncthreads();   // LDS ready; waves free-run from here (no barriers in loop)

    const short8 zed = {0, 0, 0, 0, 0, 0, 0, 0};
    auto slot = [](int t) -> size_t { return FULLT ? (size_t)t : (size_t)(t & 3); };

    for (int t = 0; t < T_; ++t) {
        if (stage == 0) {
            // ================= R0 =================
            f32x4 acc[8];
            #pragma unroll
            for (int i = 0; i < 8; ++i) acc[i] = f32x4{0.f, 0.f, 0.f, 0.f};
            const bool z = is_init[(size_t)bw * T_ + t] != 0;

            // gi0 = x @ wih0^T (independent -> before polls)
            const float* xr = x + ((size_t)bw * T_ + t) * DIN_;
            #pragma unroll
            for (int kc = 0; kc < 8; ++kc) {
                short8 bf = cvt8v(*(const f32x4*)(xr + kc * 32 + kg),
                                  *(const f32x4*)(xr + kc * 32 + kg + 4));
                chunk6<KP0_, 4>(wlds2, l15, kg, kc, bf, acc);
            }

            // per-wave dataflow waits (FULLT: sibling chain only — free-running)
            {
                const int* p = nullptr;
                if (t > 0 && lane < 16) p = &fh0[FIDX(t - 1, bt, lane, w)];
                else if (!FULLT && t >= 4 && lane >= 32 && lane < 48)
                    p = &fgi1[FIDX(t - 4, bt, lane - 32, w)];   // ring backpressure (fallback only)
                pollw(p);
                asm volatile("" ::: "memory");
                __builtin_amdgcn_sched_barrier(0);
            }

            // gh0 over h0[t-1]
            if (t == 0) {
                const float* hr = h_in + (size_t)bw * 2 * H_;
                #pragma unroll
                for (int kc = 0; kc < 16; ++kc) {
                    short8 bf = z ? zed : cvt8v(*(const f32x4*)(hr + kc * 32 + kg),
                                                *(const f32x4*)(hr + kc * 32 + kg + 4));
                    chunk6<KP_, 6>(wlds, l15, kg, kc, bf, acc);
                }
            } else {
                const __hip_bfloat16* tb = h0r + ((slot(t - 1) * 32 + b16) * 16) * 512 + lane * 8;
                gather16d<6>(tb, wlds, l15, kg, z, acc);
            }

            // fuse + publish h0[t] (per-wave)
            __hip_bfloat16* hw = h0r + ((slot(t) * 32 + b16) * 16 + jp) * 512;
            #pragma unroll
            for (int jh = 0; jh < 2; ++jh) {
                const int j4 = jb + jh * 16 + qr4;
                f32x4 hv;
                #pragma unroll
                for (int r = 0; r < 4; ++r) {
                    const float rr = sigm(acc[jh][r] + bR[jh][r]);
                    const float zz = sigm(acc[2 + jh][r] + bZ[jh][r]);
                    const float nn = tanhf(acc[4 + jh][r] + bIN[jh][r] + rr * (acc[6 + jh][r] + bHN[jh][r]));
                    const float hprev = z ? 0.0f : hp[jh][r];
                    hv[r] = (1.0f - zz) * nn + zz * hprev;
                }
                hp[jh] = hv;
                union { unsigned short us[4]; unsigned long long u; } pk;
                pk.us[0] = f2bf(hv[0]); pk.us[1] = f2bf(hv[1]);
                pk.us[2] = f2bf(hv[2]); pk.us[3] = f2bf(hv[3]);
                const int qp = jh * 2 + (q >> 1);
                store_sc8u(hw + (qp * 16 + l15) * 8 + (q & 1) * 4, pk.u);
                if (t == T_ - 1)
                    *(f32x4*)&out[OUT_MAIN + (size_t)bw * 2 * H_ + j4] = hv;
            }
            asm volatile("s_waitcnt vmcnt(0)" ::: "memory");
            __builtin_amdgcn_sched_barrier(0);
            if (lane == 0)
                __hip_atomic_store(&fh0[FIDX(t, bt, jp, w)], 1, __ATOMIC_RELAXED, __HIP_MEMORY_SCOPE_AGENT);
        } else if (stage == 2) {
            // ================= G1 =================
            f32x4 acc[6];
            #pragma unroll
            for (int i = 0; i < 6; ++i) acc[i] = f32x4{0.f, 0.f, 0.f, 0.f};
            {
                const int* p = nullptr;
                if (lane < 16)                 p = &fh0[FIDX(t, bt, lane, w)];
                else if (t >= 4 && lane == 16) p = &fh1[FIDX(t - 4, bt, jp, w)];  // gi1 ring guard
                pollw(p);
                asm volatile("" ::: "memory");
                __builtin_amdgcn_sched_barrier(0);
            }
            const __hip_bfloat16* tb = h0r + ((slot(t) * 32 + b16) * 16) * 512 + lane * 8;
            gather16d<4>(tb, wlds, l15, kg, false, acc);

            __hip_bfloat16* slab = gi1 + (((size_t)(t & 3) * 4 + bt) * 16 + jp) * GISLAB;
            #pragma unroll
            for (int jf = 0; jf < 6; ++jf)
                store_sc8(slab + ((jf * 8 + w) * 64 + lane) * 4, acc[jf]);
            asm volatile("s_waitcnt vmcnt(0)" ::: "memory");
            __builtin_amdgcn_sched_barrier(0);
            if (lane == 0)
                __hip_atomic_store(&fgi1[FIDX(t, bt, jp, w)], 1, __ATOMIC_RELAXED, __HIP_MEMORY_SCOPE_AGENT);
        } else {
            // ================= R1 =================
            f32x4 acc[6];
            #pragma unroll
            for (int i = 0; i < 6; ++i) acc[i] = f32x4{0.f, 0.f, 0.f, 0.f};
            const bool z = is_init[(size_t)bw * T_ + t] != 0;
            {
                const int* p = nullptr;
                if (t > 0 && lane < 16) p = &fh1[FIDX(t - 1, bt, lane, w)];
                else if (lane == 16)    p = &fgi1[FIDX(t, bt, jp, w)];
                pollw(p);
                asm volatile("" ::: "memory");
                __builtin_amdgcn_sched_barrier(0);
            }
            const __hip_bfloat16* slab = gi1 + (((size_t)(t & 3) * 4 + bt) * 16 + jp) * GISLAB;
            unsigned long long gu[6];
            #pragma unroll
            for (int jf = 0; jf < 6; ++jf)
                gu[jf] = load_sc8(slab + ((jf * 8 + w) * 64 + lane) * 4);

            if (t == 0) {
                const float* hr = h_in + (size_t)bw * 2 * H_ + H_;
                #pragma unroll
                for (int kc = 0; kc < 16; ++kc) {
                    short8 bf = z ? zed : cvt8v(*(const f32x4*)(hr + kc * 32 + kg),
                                                *(const f32x4*)(hr + kc * 32 + kg + 4));
                    chunk6<KP_, 4>(wlds, l15, kg, kc, bf, acc);
                }
            } else {
                const __hip_bfloat16* tb = h1r + ((slot(t - 1) * 32 + b16) * 16) * 512 + lane * 8;
                gather16d<4>(tb, wlds, l15, kg, z, acc);
            }

            __hip_bfloat16* hw = h1r + ((slot(t) * 32 + b16) * 16 + jp) * 512;
            #pragma unroll
            for (int jh = 0; jh < 2; ++jh) {
                const int j4 = jb + jh * 16 + qr4;
                const f32x4 giR = unpk(gu[jh]);
                const f32x4 giZ = unpk(gu[2 + jh]);
                const f32x4 giN = unpk(gu[4 + jh]);
                f32x4 hv;
                #pragma unroll
                for (int r = 0; r < 4; ++r) {
                    const float rr = sigm(giR[r] + acc[jh][r] + bR[jh][r]);
                    const float zz = sigm(giZ[r] + acc[2 + jh][r] + bZ[jh][r]);
                    const float nn = tanhf(giN[r] + bIN[jh][r] + rr * (acc[4 + jh][r] + bHN[jh][r]));
                    const float hprev = z ? 0.0f : hp[jh][r];
                    hv[r] = (1.0f - zz) * nn + zz * hprev;
                }
                hp[jh] = hv;
                union { unsigned short us[4]; unsigned long long u; } pk;
                pk.us[0] = f2bf(hv[0]); pk.us[1] = f2bf(hv[1]);
                pk.us[2] = f2bf(hv[2]); pk.us[3] = f2bf(hv[3]);
                const int qp = jh * 2 + (q >> 1);
                store_sc8u(hw + (qp * 16 + l15) * 8 + (q & 1) * 4, pk.u);
                *(f32x4*)&out[((size_t)bw * T_ + t) * H_ + j4] = hv;
                if (t == T_ - 1)
                    *(f32x4*)&out[OUT_MAIN + (size_t)bw * 2 * H_ + H_ + j4] = hv;
            }
            asm volatile("s_waitcnt vmcnt(0)" ::: "memory");
            __builtin_amdgcn_sched_barrier(0);
            if (lane == 0)
                __hip_atomic_store(&fh1[FIDX(t, bt, jp, w)], 1, __ATOMIC_RELAXED, __HIP_MEMORY_SCOPE_AGENT);
        }
    }
}

extern "C" void kernel_launch(void* const* d_in, const int* in_sizes, int n_in,
                              void* d_out, int out_size, void* d_ws, size_t ws_size,
                              hipStream_t stream) {
    (void)in_sizes; (void)n_in; (void)out_size;
    const float* x    = (const float*)d_in[0];
    const int*   isin = (const int*)d_in[1];
    const float* h_in = (const float*)d_in[2];
    const float* wih0 = (const float*)d_in[3];
    const float* whh0 = (const float*)d_in[4];
    const float* bih0 = (const float*)d_in[5];
    const float* bhh0 = (const float*)d_in[6];
    const float* wih1 = (const float*)d_in[7];
    const float* whh1 = (const float*)d_in[8];
    const float* bih1 = (const float*)d_in[9];
    const float* bhh1 = (const float*)d_in[10];
    float* out = (float*)d_out;
    char* ws = (char*)d_ws;

    const bool fullt = ws_size >= (144ull << 20);
    int* flg = (int*)(ws + (fullt ? 141557760ull : 16777216ull));

    init_kernel<<<dim3(256), dim3(256), 0, stream>>>(flg);

    if (fullt)
        gru_wave<true><<<dim3(256), dim3(512), 0, stream>>>(
            x, isin, h_in, wih0, whh0, bih0, bhh0,
            wih1, whh1, bih1, bhh1, ws, out);
    else
        gru_wave<false><<<dim3(256), dim3(512), 0, stream>>>(
            x, isin, h_in, wih0, whh0, bih0, bhh0,
            wih1, whh1, bih1, bhh1, ws, out);
}

// Round 16
// 1488.006 us; speedup vs baseline: 1.2053x; 1.2053x over previous
//
#include <hip/hip_runtime.h>
#include <hip/hip_bf16.h>

#define B_ 512
#define T_ 128
#define DIN_ 256
#define H_ 512
#define KP_ 520             // LDS stride (bf16) K=512 weights
#define KP0_ 264            // LDS stride K=256 (wih0)
#define OUT_MAIN ((size_t)B_ * T_ * H_)
#define GISLAB 12288
#define NFLG 196608

// ws byte offsets (R12 layout)
#define OFF_H1  2097152ull
#define OFF_GI1 4194304ull
#define OFF_FLG 16777216ull

typedef __attribute__((ext_vector_type(8))) short short8;
typedef __attribute__((ext_vector_type(4))) float f32x4;

__device__ __forceinline__ float sigm(float v) { return 1.0f / (1.0f + __expf(-v)); }

__device__ __forceinline__ unsigned short f2bf(float f) {
    union { __hip_bfloat16 b; unsigned short u; } c;
    c.b = __float2bfloat16(f);
    return c.u;
}

__device__ __forceinline__ short8 cvt8v(f32x4 u, f32x4 v) {
    short8 o;
    o[0] = (short)f2bf(u[0]); o[1] = (short)f2bf(u[1]);
    o[2] = (short)f2bf(u[2]); o[3] = (short)f2bf(u[3]);
    o[4] = (short)f2bf(v[0]); o[5] = (short)f2bf(v[1]);
    o[6] = (short)f2bf(v[2]); o[7] = (short)f2bf(v[3]);
    return o;
}

// coherent-point (sc0 sc1) loads — fastest correct transport (R12 vs R13/R14/R15)
__device__ __forceinline__ short8 ldh(const __hip_bfloat16* p) {
    short8 r;
    asm volatile("global_load_dwordx4 %0, %1, off sc0 sc1" : "=v"(r) : "v"(p));
    return r;
}
__device__ __forceinline__ unsigned long long ld8a(const __hip_bfloat16* p) {
    unsigned long long r;
    asm volatile("global_load_dwordx2 %0, %1, off sc0 sc1" : "=v"(r) : "v"(p));
    return r;
}
#define VMWAIT(N) do { asm volatile("s_waitcnt vmcnt(" #N ")" ::: "memory"); \
                       __builtin_amdgcn_sched_barrier(0); } while (0)

__device__ __forceinline__ unsigned long long load_sc8(const __hip_bfloat16* p) {
    return __hip_atomic_load((const unsigned long long*)p, __ATOMIC_RELAXED, __HIP_MEMORY_SCOPE_AGENT);
}
__device__ __forceinline__ void store_sc8u(__hip_bfloat16* p, unsigned long long v) {
    __hip_atomic_store((unsigned long long*)p, v, __ATOMIC_RELAXED, __HIP_MEMORY_SCOPE_AGENT);
}
__device__ __forceinline__ void store_sc8(__hip_bfloat16* p, f32x4 h4) {
    union { unsigned short s[4]; unsigned long long u; } r;
    r.s[0] = f2bf(h4[0]); r.s[1] = f2bf(h4[1]);
    r.s[2] = f2bf(h4[2]); r.s[3] = f2bf(h4[3]);
    store_sc8u(p, r.u);
}

__device__ __forceinline__ f32x4 unpk(unsigned long long u) {
    f32x4 r;
    r[0] = __uint_as_float((unsigned)(u & 0xffffull) << 16);
    r[1] = __uint_as_float((unsigned)((u >> 16) & 0xffffull) << 16);
    r[2] = __uint_as_float((unsigned)((u >> 32) & 0xffffull) << 16);
    r[3] = __uint_as_float((unsigned)((u >> 48) & 0xffffull) << 16);
    return r;
}

__device__ __forceinline__ void pollw(const int* p) {
    if (p)
        while (__hip_atomic_load(p, __ATOMIC_RELAXED, __HIP_MEMORY_SCOPE_AGENT) == 0)
            __builtin_amdgcn_s_sleep(1);
}

#define FIDX(t, bt, jp, w) (((((t) * 4 + (bt)) * 16 + (jp)) * 8) + (w))

__global__ void init_kernel(int* __restrict__ flg)
{
    int i = blockIdx.x * blockDim.x + threadIdx.x;
    int stride = gridDim.x * blockDim.x;
    for (int k = i; k < NFLG; k += stride)
        __hip_atomic_store(&flg[k], 0, __ATOMIC_RELAXED, __HIP_MEMORY_SCOPE_AGENT);
}

// acc: 0,1 = r ; 2,3 = z ; NB,NB+1 = n
template<int KP, int NB>
__device__ __forceinline__ void chunk6(const __hip_bfloat16* wl, int l15, int kg, int kc,
                                       short8 bf, f32x4* acc) {
    #pragma unroll
    for (int g = 0; g < 3; ++g) {
        const int ai = (g == 2) ? NB : g * 2;
        #pragma unroll
        for (int jh = 0; jh < 2; ++jh) {
            short8 wf = *(const short8*)&wl[(size_t)(g * 32 + jh * 16 + l15) * KP + kc * 32 + kg];
            acc[ai + jh] = __builtin_amdgcn_mfma_f32_16x16x32_bf16(wf, bf, acc[ai + jh], 0, 0, 0);
        }
    }
}

// G1's gather: issue all 16, counted drains (R12-proven)
template<int NB>
__device__ __forceinline__ void gather16d(const __hip_bfloat16* tb, const __hip_bfloat16* wl,
                                          int l15, int kg, bool z, f32x4* acc)
{
    const short8 zed = {0,0,0,0,0,0,0,0};
    VMWAIT(0);   // honest vmcnt baseline
    short8 v[16];
    #pragma unroll
    for (int i = 0; i < 16; ++i) v[i] = ldh(tb + i * 512);
    VMWAIT(12);
    #pragma unroll
    for (int i = 0; i < 4; ++i)  chunk6<KP_, NB>(wl, l15, kg, i, z ? zed : v[i], acc);
    VMWAIT(8);
    #pragma unroll
    for (int i = 4; i < 8; ++i)  chunk6<KP_, NB>(wl, l15, kg, i, z ? zed : v[i], acc);
    VMWAIT(4);
    #pragma unroll
    for (int i = 8; i < 12; ++i) chunk6<KP_, NB>(wl, l15, kg, i, z ? zed : v[i], acc);
    VMWAIT(0);
    #pragma unroll
    for (int i = 12; i < 16; ++i) chunk6<KP_, NB>(wl, l15, kg, i, z ? zed : v[i], acc);
}

// 256 blocks x 512 threads. R12 decode (stages SPREAD across XCDs — clustering
// regressed, R13-R15): stage=bid>>6: 0=R0, 1=R1, 2=G1, 3=exit. bt=(bid>>4)&3,
// jp=bid&15. Per-wave dataflow flags, no __syncthreads in t-loop. New in R16:
// R0 prefetches x[t+1] to registers (gi0 = pure LDS+MFMA) and issues the 16
// gather loads BEFORE gi0 so compute hides the L3 round trip; R1 folds its 6
// slab loads into the gather's vmcnt ladder.
__global__ __launch_bounds__(512) void gru_wave(
    const float* __restrict__ x, const int* __restrict__ is_init,
    const float* __restrict__ h_in,
    const float* __restrict__ wih0, const float* __restrict__ whh0,
    const float* __restrict__ bih0, const float* __restrict__ bhh0,
    const float* __restrict__ wih1, const float* __restrict__ whh1,
    const float* __restrict__ bih1, const float* __restrict__ bhh1,
    char* __restrict__ ws, float* __restrict__ out)
{
    __shared__ __hip_bfloat16 wsh[96 * KP_ + 96 * KP0_];   // 150528 B

    const int bid = blockIdx.x;
    const int stage = bid >> 6;
    if (stage == 3) return;
    const int bt = (bid >> 4) & 3;
    const int jp = bid & 15;

    __hip_bfloat16* h0r = (__hip_bfloat16*)ws;                 // [4][32][16][512]
    __hip_bfloat16* h1r = (__hip_bfloat16*)(ws + OFF_H1);
    __hip_bfloat16* gi1 = (__hip_bfloat16*)(ws + OFF_GI1);     // [4][4][16][12288]
    int* flg  = (int*)(ws + OFF_FLG);
    int* fh0  = flg;
    int* fh1  = flg + 65536;
    int* fgi1 = flg + 131072;

    const int tid = threadIdx.x;
    const int lane = tid & 63;
    const int w = tid >> 6;
    const int l15 = lane & 15;
    const int q = lane >> 4;
    const int kg = q * 8;
    const int qr4 = q * 4;
    const int rb = bt * 128;
    const int jb = jp * 32;
    const int bw = rb + w * 16 + l15;
    const int b16 = bt * 8 + w;

    // ---- stage weights into LDS (f32 -> bf16), once ----
    __hip_bfloat16* wlds  = wsh;
    __hip_bfloat16* wlds2 = wsh + 96 * KP_;
    {
        const float* Wsrc = (stage == 0) ? whh0 : (stage == 1) ? whh1 : wih1;
        for (int ii = tid; ii < 96 * 64; ii += 512) {
            int gr = ii >> 6, c8 = ii & 63;
            int grow = (gr >> 5) * H_ + jb + (gr & 31);
            const float* p = Wsrc + (size_t)grow * H_ + c8 * 8;
            *(short8*)&wlds[(size_t)gr * KP_ + c8 * 8] = cvt8v(*(const f32x4*)p, *(const f32x4*)(p + 4));
        }
        if (stage == 0) {
            for (int ii = tid; ii < 96 * 32; ii += 512) {
                int gr = ii >> 5, c8 = ii & 31;
                int grow = (gr >> 5) * H_ + jb + (gr & 31);
                const float* p = wih0 + (size_t)grow * DIN_ + c8 * 8;
                *(short8*)&wlds2[(size_t)gr * KP0_ + c8 * 8] = cvt8v(*(const f32x4*)p, *(const f32x4*)(p + 4));
            }
        }
    }

    // ---- per-lane constants for R stages ----
    f32x4 bR[2], bZ[2], bIN[2], bHN[2], hp[2];
    if (stage < 2) {
        const float* bi = stage ? bih1 : bih0;
        const float* bh = stage ? bhh1 : bhh0;
        #pragma unroll
        for (int jh = 0; jh < 2; ++jh) {
            const int j4 = jb + jh * 16 + qr4;
            bR[jh]  = *(const f32x4*)&bi[j4]          + *(const f32x4*)&bh[j4];
            bZ[jh]  = *(const f32x4*)&bi[H_ + j4]     + *(const f32x4*)&bh[H_ + j4];
            bIN[jh] = *(const f32x4*)&bi[2 * H_ + j4];
            bHN[jh] = *(const f32x4*)&bh[2 * H_ + j4];
            hp[jh]  = *(const f32x4*)&h_in[(size_t)bw * 2 * H_ + (size_t)stage * H_ + j4];
        }
    }

    // ---- R0: prefetch x[0] into registers (bf16-converted) ----
    short8 xv[8];
    if (stage == 0) {
        const float* xr = x + ((size_t)bw * T_) * DIN_;
        #pragma unroll
        for (int kc = 0; kc < 8; ++kc)
            xv[kc] = cvt8v(*(const f32x4*)(xr + kc * 32 + kg),
                           *(const f32x4*)(xr + kc * 32 + kg + 4));
    }
    __syncthreads();   // LDS ready; waves free-run from here

    const short8 zed = {0, 0, 0, 0, 0, 0, 0, 0};

    for (int t = 0; t < T_; ++t) {
        if (stage == 0) {
            // ================= R0 =================
            f32x4 acc[8];
            #pragma unroll
            for (int i = 0; i < 8; ++i) acc[i] = f32x4{0.f, 0.f, 0.f, 0.f};
            int zi = is_init[(size_t)bw * T_ + t];
            asm volatile("" : "+v"(zi));          // materialize before asm region
            const bool z = zi != 0;

            // per-wave dataflow waits
            {
                const int* p = nullptr;
                if (t > 0 && lane < 16)                     p = &fh0[FIDX(t - 1, bt, lane, w)];
                else if (t >= 4 && lane >= 32 && lane < 48) p = &fgi1[FIDX(t - 4, bt, lane - 32, w)];
                pollw(p);
                asm volatile("" ::: "memory");
                __builtin_amdgcn_sched_barrier(0);
            }

            if (t == 0) {
                #pragma unroll
                for (int kc = 0; kc < 8; ++kc)
                    chunk6<KP0_, 4>(wlds2, l15, kg, kc, xv[kc], acc);
                const float* hr = h_in + (size_t)bw * 2 * H_;
                #pragma unroll
                for (int kc = 0; kc < 16; ++kc) {
                    short8 bf = z ? zed : cvt8v(*(const f32x4*)(hr + kc * 32 + kg),
                                                *(const f32x4*)(hr + kc * 32 + kg + 4));
                    chunk6<KP_, 6>(wlds, l15, kg, kc, bf, acc);
                }
            } else {
                // issue gather FIRST, hide latency under gi0 (pure LDS+MFMA)
                const __hip_bfloat16* tb = h0r + (((size_t)((t - 1) & 3) * 32 + b16) * 16) * 512 + lane * 8;
                short8 v[16];
                #pragma unroll
                for (int i = 0; i < 16; ++i) v[i] = ldh(tb + i * 512);
                #pragma unroll
                for (int kc = 0; kc < 8; ++kc)
                    chunk6<KP0_, 4>(wlds2, l15, kg, kc, xv[kc], acc);
                VMWAIT(12);
                #pragma unroll
                for (int i = 0; i < 4; ++i)  chunk6<KP_, 6>(wlds, l15, kg, i, z ? zed : v[i], acc);
                VMWAIT(8);
                #pragma unroll
                for (int i = 4; i < 8; ++i)  chunk6<KP_, 6>(wlds, l15, kg, i, z ? zed : v[i], acc);
                VMWAIT(4);
                #pragma unroll
                for (int i = 8; i < 12; ++i) chunk6<KP_, 6>(wlds, l15, kg, i, z ? zed : v[i], acc);
                VMWAIT(0);
                #pragma unroll
                for (int i = 12; i < 16; ++i) chunk6<KP_, 6>(wlds, l15, kg, i, z ? zed : v[i], acc);
            }

            // fuse + publish h0[t] (per-wave)
            __hip_bfloat16* hw = h0r + (((size_t)(t & 3) * 32 + b16) * 16 + jp) * 512;
            #pragma unroll
            for (int jh = 0; jh < 2; ++jh) {
                const int j4 = jb + jh * 16 + qr4;
                f32x4 hv;
                #pragma unroll
                for (int r = 0; r < 4; ++r) {
                    const float rr = sigm(acc[jh][r] + bR[jh][r]);
                    const float zz = sigm(acc[2 + jh][r] + bZ[jh][r]);
                    const float nn = tanhf(acc[4 + jh][r] + bIN[jh][r] + rr * (acc[6 + jh][r] + bHN[jh][r]));
                    const float hprev = z ? 0.0f : hp[jh][r];
                    hv[r] = (1.0f - zz) * nn + zz * hprev;
                }
                hp[jh] = hv;
                union { unsigned short us[4]; unsigned long long u; } pk;
                pk.us[0] = f2bf(hv[0]); pk.us[1] = f2bf(hv[1]);
                pk.us[2] = f2bf(hv[2]); pk.us[3] = f2bf(hv[3]);
                const int qp = jh * 2 + (q >> 1);
                store_sc8u(hw + (qp * 16 + l15) * 8 + (q & 1) * 4, pk.u);
                if (t == T_ - 1)
                    *(f32x4*)&out[OUT_MAIN + (size_t)bw * 2 * H_ + j4] = hv;
            }
            asm volatile("s_waitcnt vmcnt(0)" ::: "memory");
            __builtin_amdgcn_sched_barrier(0);
            if (lane == 0)
                __hip_atomic_store(&fh0[FIDX(t, bt, jp, w)], 1, __ATOMIC_RELAXED, __HIP_MEMORY_SCOPE_AGENT);
            VMWAIT(0);   // drain flag store -> honest vmcnt baseline next iter

            // prefetch x[t+1] (overlaps flag propagation; off the serial chain)
            if (t + 1 < T_) {
                const float* xr = x + ((size_t)bw * T_ + t + 1) * DIN_;
                #pragma unroll
                for (int kc = 0; kc < 8; ++kc)
                    xv[kc] = cvt8v(*(const f32x4*)(xr + kc * 32 + kg),
                                   *(const f32x4*)(xr + kc * 32 + kg + 4));
                __builtin_amdgcn_sched_barrier(0);
            }
        } else if (stage == 2) {
            // ================= G1 =================
            f32x4 acc[6];
            #pragma unroll
            for (int i = 0; i < 6; ++i) acc[i] = f32x4{0.f, 0.f, 0.f, 0.f};
            {
                const int* p = nullptr;
                if (lane < 16)                 p = &fh0[FIDX(t, bt, lane, w)];
                else if (t >= 4 && lane == 16) p = &fh1[FIDX(t - 4, bt, jp, w)];  // gi1 ring guard
                pollw(p);
                asm volatile("" ::: "memory");
                __builtin_amdgcn_sched_barrier(0);
            }
            const __hip_bfloat16* tb = h0r + (((size_t)(t & 3) * 32 + b16) * 16) * 512 + lane * 8;
            gather16d<4>(tb, wlds, l15, kg, false, acc);

            __hip_bfloat16* slab = gi1 + (((size_t)(t & 3) * 4 + bt) * 16 + jp) * GISLAB;
            #pragma unroll
            for (int jf = 0; jf < 6; ++jf)
                store_sc8(slab + ((jf * 8 + w) * 64 + lane) * 4, acc[jf]);
            asm volatile("s_waitcnt vmcnt(0)" ::: "memory");
            __builtin_amdgcn_sched_barrier(0);
            if (lane == 0)
                __hip_atomic_store(&fgi1[FIDX(t, bt, jp, w)], 1, __ATOMIC_RELAXED, __HIP_MEMORY_SCOPE_AGENT);
        } else {
            // ================= R1 =================
            f32x4 acc[6];
            #pragma unroll
            for (int i = 0; i < 6; ++i) acc[i] = f32x4{0.f, 0.f, 0.f, 0.f};
            int zi = is_init[(size_t)bw * T_ + t];
            asm volatile("" : "+v"(zi));
            const bool z = zi != 0;
            {
                const int* p = nullptr;
                if (t > 0 && lane < 16) p = &fh1[FIDX(t - 1, bt, lane, w)];
                else if (lane == 16)    p = &fgi1[FIDX(t, bt, jp, w)];
                pollw(p);
                asm volatile("" ::: "memory");
                __builtin_amdgcn_sched_barrier(0);
            }
            const __hip_bfloat16* slab = gi1 + (((size_t)(t & 3) * 4 + bt) * 16 + jp) * GISLAB;
            unsigned long long gu[6];

            if (t == 0) {
                #pragma unroll
                for (int jf = 0; jf < 6; ++jf)
                    gu[jf] = load_sc8(slab + ((jf * 8 + w) * 64 + lane) * 4);
                const float* hr = h_in + (size_t)bw * 2 * H_ + H_;
                #pragma unroll
                for (int kc = 0; kc < 16; ++kc) {
                    short8 bf = z ? zed : cvt8v(*(const f32x4*)(hr + kc * 32 + kg),
                                                *(const f32x4*)(hr + kc * 32 + kg + 4));
                    chunk6<KP_, 4>(wlds, l15, kg, kc, bf, acc);
                }
            } else {
                // 16 gather tiles + 6 slab loads in one counted-vmcnt ladder
                const __hip_bfloat16* tb = h1r + (((size_t)((t - 1) & 3) * 32 + b16) * 16) * 512 + lane * 8;
                short8 v[16];
                #pragma unroll
                for (int i = 0; i < 16; ++i) v[i] = ldh(tb + i * 512);
                #pragma unroll
                for (int jf = 0; jf < 6; ++jf)
                    gu[jf] = ld8a(slab + ((jf * 8 + w) * 64 + lane) * 4);
                VMWAIT(18);
                #pragma unroll
                for (int i = 0; i < 4; ++i)  chunk6<KP_, 4>(wlds, l15, kg, i, z ? zed : v[i], acc);
                VMWAIT(14);
                #pragma unroll
                for (int i = 4; i < 8; ++i)  chunk6<KP_, 4>(wlds, l15, kg, i, z ? zed : v[i], acc);
                VMWAIT(10);
                #pragma unroll
                for (int i = 8; i < 12; ++i) chunk6<KP_, 4>(wlds, l15, kg, i, z ? zed : v[i], acc);
                VMWAIT(6);
                #pragma unroll
                for (int i = 12; i < 16; ++i) chunk6<KP_, 4>(wlds, l15, kg, i, z ? zed : v[i], acc);
                VMWAIT(0);   // slabs ready
            }

            __hip_bfloat16* hw = h1r + (((size_t)(t & 3) * 32 + b16) * 16 + jp) * 512;
            #pragma unroll
            for (int jh = 0; jh < 2; ++jh) {
                const int j4 = jb + jh * 16 + qr4;
                const f32x4 giR = unpk(gu[jh]);
                const f32x4 giZ = unpk(gu[2 + jh]);
                const f32x4 giN = unpk(gu[4 + jh]);
                f32x4 hv;
                #pragma unroll
                for (int r = 0; r < 4; ++r) {
                    const float rr = sigm(giR[r] + acc[jh][r] + bR[jh][r]);
                    const float zz = sigm(giZ[r] + acc[2 + jh][r] + bZ[jh][r]);
                    const float nn = tanhf(giN[r] + bIN[jh][r] + rr * (acc[4 + jh][r] + bHN[jh][r]));
                    const float hprev = z ? 0.0f : hp[jh][r];
                    hv[r] = (1.0f - zz) * nn + zz * hprev;
                }
                hp[jh] = hv;
                union { unsigned short us[4]; unsigned long long u; } pk;
                pk.us[0] = f2bf(hv[0]); pk.us[1] = f2bf(hv[1]);
                pk.us[2] = f2bf(hv[2]); pk.us[3] = f2bf(hv[3]);
                const int qp = jh * 2 + (q >> 1);
                store_sc8u(hw + (qp * 16 + l15) * 8 + (q & 1) * 4, pk.u);
                *(f32x4*)&out[((size_t)bw * T_ + t) * H_ + j4] = hv;
                if (t == T_ - 1)
                    *(f32x4*)&out[OUT_MAIN + (size_t)bw * 2 * H_ + H_ + j4] = hv;
            }
            asm volatile("s_waitcnt vmcnt(0)" ::: "memory");
            __builtin_amdgcn_sched_barrier(0);
            if (lane == 0)
                __hip_atomic_store(&fh1[FIDX(t, bt, jp, w)], 1, __ATOMIC_RELAXED, __HIP_MEMORY_SCOPE_AGENT);
            VMWAIT(0);   // drain flag store -> honest baseline next iter
        }
    }
}

extern "C" void kernel_launch(void* const* d_in, const int* in_sizes, int n_in,
                              void* d_out, int out_size, void* d_ws, size_t ws_size,
                              hipStream_t stream) {
    (void)in_sizes; (void)n_in; (void)out_size; (void)ws_size;
    const float* x    = (const float*)d_in[0];
    const int*   isin = (const int*)d_in[1];
    const float* h_in = (const float*)d_in[2];
    const float* wih0 = (const float*)d_in[3];
    const float* whh0 = (const float*)d_in[4];
    const float* bih0 = (const float*)d_in[5];
    const float* bhh0 = (const float*)d_in[6];
    const float* wih1 = (const float*)d_in[7];
    const float* whh1 = (const float*)d_in[8];
    const float* bih1 = (const float*)d_in[9];
    const float* bhh1 = (const float*)d_in[10];
    float* out = (float*)d_out;
    char* ws = (char*)d_ws;

    init_kernel<<<dim3(256), dim3(256), 0, stream>>>((int*)(ws + OFF_FLG));

    gru_wave<<<dim3(256), dim3(512), 0, stream>>>(
        x, isin, h_in,
        wih0, whh0, bih0, bhh0,
        wih1, whh1, bih1, bhh1,
        ws, out);
}

// Round 17
// 1353.060 us; speedup vs baseline: 1.3255x; 1.0997x over previous
//
#include <hip/hip_runtime.h>
#include <hip/hip_bf16.h>

#define B_ 512
#define T_ 128
#define DIN_ 256
#define H_ 512
#define KP_ 520             // LDS stride (bf16) K=512 weights
#define KP0_ 264            // LDS stride K=256 (wih0)
#define OUT_MAIN ((size_t)B_ * T_ * H_)
#define GISLAB 12288

// ws byte offsets
#define OFF_H1  2097152ull
#define OFF_GI1 4194304ull
#define OFF_FLG 16777216ull

typedef __attribute__((ext_vector_type(8))) short short8;
typedef __attribute__((ext_vector_type(4))) float f32x4;

__device__ __forceinline__ float sigm(float v) { return 1.0f / (1.0f + __expf(-v)); }

__device__ __forceinline__ unsigned short f2bf(float f) {
    union { __hip_bfloat16 b; unsigned short u; } c;
    c.b = __float2bfloat16(f);
    return c.u;
}

__device__ __forceinline__ short8 cvt8v(f32x4 u, f32x4 v) {
    short8 o;
    o[0] = (short)f2bf(u[0]); o[1] = (short)f2bf(u[1]);
    o[2] = (short)f2bf(u[2]); o[3] = (short)f2bf(u[3]);
    o[4] = (short)f2bf(v[0]); o[5] = (short)f2bf(v[1]);
    o[6] = (short)f2bf(v[2]); o[7] = (short)f2bf(v[3]);
    return o;
}

// coherent-point (sc0 sc1) 16B load — the proven cross-XCD transport
__device__ __forceinline__ short8 ldh(const __hip_bfloat16* p) {
    short8 r;
    asm volatile("global_load_dwordx4 %0, %1, off sc0 sc1" : "=v"(r) : "v"(p));
    return r;
}
#define VMWAIT(N) do { asm volatile("s_waitcnt vmcnt(" #N ")" ::: "memory"); \
                       __builtin_amdgcn_sched_barrier(0); } while (0)

__device__ __forceinline__ unsigned long long load_sc8(const __hip_bfloat16* p) {
    return __hip_atomic_load((const unsigned long long*)p, __ATOMIC_RELAXED, __HIP_MEMORY_SCOPE_AGENT);
}
__device__ __forceinline__ void store_sc8u(__hip_bfloat16* p, unsigned long long v) {
    __hip_atomic_store((unsigned long long*)p, v, __ATOMIC_RELAXED, __HIP_MEMORY_SCOPE_AGENT);
}
__device__ __forceinline__ void store_sc8(__hip_bfloat16* p, f32x4 h4) {
    union { unsigned short s[4]; unsigned long long u; } r;
    r.s[0] = f2bf(h4[0]); r.s[1] = f2bf(h4[1]);
    r.s[2] = f2bf(h4[2]); r.s[3] = f2bf(h4[3]);
    store_sc8u(p, r.u);
}

__device__ __forceinline__ f32x4 unpk(unsigned long long u) {
    f32x4 r;
    r[0] = __uint_as_float((unsigned)(u & 0xffffull) << 16);
    r[1] = __uint_as_float((unsigned)((u >> 16) & 0xffffull) << 16);
    r[2] = __uint_as_float((unsigned)((u >> 32) & 0xffffull) << 16);
    r[3] = __uint_as_float((unsigned)((u >> 48) & 0xffffull) << 16);
    return r;
}

// divergent per-lane poll on an agent flag (nullptr = no wait)
__device__ __forceinline__ void pollw(const int* p) {
    if (p)
        while (__hip_atomic_load(p, __ATOMIC_RELAXED, __HIP_MEMORY_SCOPE_AGENT) == 0)
            __builtin_amdgcn_s_sleep(1);
}

#define FIDX(t, bt, jp, w) (((((t) * 4 + (bt)) * 16 + (jp)) * 8) + (w))

__global__ void init_kernel(int* __restrict__ flg)
{
    int i = blockIdx.x * blockDim.x + threadIdx.x;
    int stride = gridDim.x * blockDim.x;
    for (int k = i; k < 196608; k += stride)
        __hip_atomic_store(&flg[k], 0, __ATOMIC_RELAXED, __HIP_MEMORY_SCOPE_AGENT);
}

// acc: 0,1 = r ; 2,3 = z ; NB,NB+1 = n
template<int KP, int NB>
__device__ __forceinline__ void chunk6(const __hip_bfloat16* wl, int l15, int kg, int kc,
                                       short8 bf, f32x4* acc) {
    #pragma unroll
    for (int g = 0; g < 3; ++g) {
        const int ai = (g == 2) ? NB : g * 2;
        #pragma unroll
        for (int jh = 0; jh < 2; ++jh) {
            short8 wf = *(const short8*)&wl[(size_t)(g * 32 + jh * 16 + l15) * KP + kc * 32 + kg];
            acc[ai + jh] = __builtin_amdgcn_mfma_f32_16x16x32_bf16(wf, bf, acc[ai + jh], 0, 0, 0);
        }
    }
}

// 16-deep pipelined gather of 16 x 1KB tiles (issue all, counted drains)
template<int NB>
__device__ __forceinline__ void gather16d(const __hip_bfloat16* tb, const __hip_bfloat16* wl,
                                          int l15, int kg, bool z, f32x4* acc)
{
    const short8 zed = {0,0,0,0,0,0,0,0};
    VMWAIT(0);   // honest vmcnt baseline (drains prior flag/slab ops)
    short8 v[16];
    #pragma unroll
    for (int i = 0; i < 16; ++i) v[i] = ldh(tb + i * 512);
    VMWAIT(12);
    #pragma unroll
    for (int i = 0; i < 4; ++i)  chunk6<KP_, NB>(wl, l15, kg, i, z ? zed : v[i], acc);
    VMWAIT(8);
    #pragma unroll
    for (int i = 4; i < 8; ++i)  chunk6<KP_, NB>(wl, l15, kg, i, z ? zed : v[i], acc);
    VMWAIT(4);
    #pragma unroll
    for (int i = 8; i < 12; ++i) chunk6<KP_, NB>(wl, l15, kg, i, z ? zed : v[i], acc);
    VMWAIT(0);
    #pragma unroll
    for (int i = 12; i < 16; ++i) chunk6<KP_, NB>(wl, l15, kg, i, z ? zed : v[i], acc);
}

// 256 blocks x 512 threads, stage = bid>>6: 0=R0 (gi0 local + gh0 + fuse -> h0),
// 1=R1 (gh1 + gi1 slab + fuse -> out), 2=G1 (gi1 = h0 @ wih1^T), 3=exit.
// bt=(bid>>4)&3, jp=bid&15. 8 waves = 8 disjoint 16-row groups; ALL dataflow is
// per-wave (flags [t][bt][jp][w]); no __syncthreads in the t-loop.
__global__ __launch_bounds__(512) void gru_wave(
    const float* __restrict__ x, const int* __restrict__ is_init,
    const float* __restrict__ h_in,
    const float* __restrict__ wih0, const float* __restrict__ whh0,
    const float* __restrict__ bih0, const float* __restrict__ bhh0,
    const float* __restrict__ wih1, const float* __restrict__ whh1,
    const float* __restrict__ bih1, const float* __restrict__ bhh1,
    char* __restrict__ ws, float* __restrict__ out)
{
    __shared__ __hip_bfloat16 wsh[96 * KP_ + 96 * KP0_];   // 150528 B

    const int bid = blockIdx.x;
    const int stage = bid >> 6;
    if (stage == 3) return;
    const int bt = (bid >> 4) & 3;
    const int jp = bid & 15;

    __hip_bfloat16* h0r = (__hip_bfloat16*)ws;                 // [4][32][16][512]
    __hip_bfloat16* h1r = (__hip_bfloat16*)(ws + OFF_H1);
    __hip_bfloat16* gi1 = (__hip_bfloat16*)(ws + OFF_GI1);     // [4][4][16][12288]
    int* flg  = (int*)(ws + OFF_FLG);
    int* fh0  = flg;
    int* fh1  = flg + 65536;
    int* fgi1 = flg + 131072;

    const int tid = threadIdx.x;
    const int lane = tid & 63;
    const int w = tid >> 6;
    const int l15 = lane & 15;
    const int q = lane >> 4;
    const int kg = q * 8;
    const int qr4 = q * 4;
    const int rb = bt * 128;
    const int jb = jp * 32;
    const int bw = rb + w * 16 + l15;
    const int b16 = bt * 8 + w;

    // ---- stage weights into LDS (f32 -> bf16), once ----
    __hip_bfloat16* wlds  = wsh;
    __hip_bfloat16* wlds2 = wsh + 96 * KP_;
    {
        const float* Wsrc = (stage == 0) ? whh0 : (stage == 1) ? whh1 : wih1;
        for (int idx = tid; idx < 96 * 64; idx += 512) {
            int gr = idx >> 6, c8 = idx & 63;
            int grow = (gr >> 5) * H_ + jb + (gr & 31);
            const float* p = Wsrc + (size_t)grow * H_ + c8 * 8;
            *(short8*)&wlds[(size_t)gr * KP_ + c8 * 8] = cvt8v(*(const f32x4*)p, *(const f32x4*)(p + 4));
        }
        if (stage == 0) {
            for (int idx = tid; idx < 96 * 32; idx += 512) {
                int gr = idx >> 5, c8 = idx & 31;
                int grow = (gr >> 5) * H_ + jb + (gr & 31);
                const float* p = wih0 + (size_t)grow * DIN_ + c8 * 8;
                *(short8*)&wlds2[(size_t)gr * KP0_ + c8 * 8] = cvt8v(*(const f32x4*)p, *(const f32x4*)(p + 4));
            }
        }
    }

    // ---- per-lane constants for R stages ----
    f32x4 bR[2], bZ[2], bIN[2], bHN[2], hp[2];
    if (stage < 2) {
        const float* bi = stage ? bih1 : bih0;
        const float* bh = stage ? bhh1 : bhh0;
        #pragma unroll
        for (int jh = 0; jh < 2; ++jh) {
            const int j4 = jb + jh * 16 + qr4;
            bR[jh]  = *(const f32x4*)&bi[j4]          + *(const f32x4*)&bh[j4];
            bZ[jh]  = *(const f32x4*)&bi[H_ + j4]     + *(const f32x4*)&bh[H_ + j4];
            bIN[jh] = *(const f32x4*)&bi[2 * H_ + j4];
            bHN[jh] = *(const f32x4*)&bh[2 * H_ + j4];
            hp[jh]  = *(const f32x4*)&h_in[(size_t)bw * 2 * H_ + (size_t)stage * H_ + j4];
        }
    }
    __syncthreads();   // LDS weights ready; last sync — waves free-run from here

    const short8 zed = {0, 0, 0, 0, 0, 0, 0, 0};

    for (int t = 0; t < T_; ++t) {
        if (stage == 0) {
            // ================= R0 =================
            f32x4 acc[8];
            #pragma unroll
            for (int i = 0; i < 8; ++i) acc[i] = f32x4{0.f, 0.f, 0.f, 0.f};
            const bool z = is_init[(size_t)bw * T_ + t] != 0;

            // gi0 = x @ wih0^T (independent -> before polls)
            const float* xr = x + ((size_t)bw * T_ + t) * DIN_;
            #pragma unroll
            for (int kc = 0; kc < 8; ++kc) {
                short8 bf = cvt8v(*(const f32x4*)(xr + kc * 32 + kg),
                                  *(const f32x4*)(xr + kc * 32 + kg + 4));
                chunk6<KP0_, 4>(wlds2, l15, kg, kc, bf, acc);
            }

            // per-wave dataflow waits
            {
                const int* p = nullptr;
                if (t > 0 && lane < 16)                       p = &fh0[FIDX(t - 1, bt, lane, w)];
                else if (t >= 4 && lane >= 32 && lane < 48)   p = &fgi1[FIDX(t - 4, bt, lane - 32, w)];
                pollw(p);
                asm volatile("" ::: "memory");
                __builtin_amdgcn_sched_barrier(0);
            }

            // gh0 over h0[t-1]
            if (t == 0) {
                const float* hr = h_in + (size_t)bw * 2 * H_;
                #pragma unroll
                for (int kc = 0; kc < 16; ++kc) {
                    short8 bf = z ? zed : cvt8v(*(const f32x4*)(hr + kc * 32 + kg),
                                                *(const f32x4*)(hr + kc * 32 + kg + 4));
                    chunk6<KP_, 6>(wlds, l15, kg, kc, bf, acc);
                }
            } else {
                const __hip_bfloat16* tb = h0r + (((size_t)((t - 1) & 3) * 32 + b16) * 16) * 512 + lane * 8;
                gather16d<6>(tb, wlds, l15, kg, z, acc);
            }

            // fuse + publish h0[t] (per-wave)
            __hip_bfloat16* hw = h0r + (((size_t)(t & 3) * 32 + b16) * 16 + jp) * 512;
            #pragma unroll
            for (int jh = 0; jh < 2; ++jh) {
                const int j4 = jb + jh * 16 + qr4;
                f32x4 hv;
                #pragma unroll
                for (int r = 0; r < 4; ++r) {
                    const float rr = sigm(acc[jh][r] + bR[jh][r]);
                    const float zz = sigm(acc[2 + jh][r] + bZ[jh][r]);
                    const float nn = tanhf(acc[4 + jh][r] + bIN[jh][r] + rr * (acc[6 + jh][r] + bHN[jh][r]));
                    const float hprev = z ? 0.0f : hp[jh][r];
                    hv[r] = (1.0f - zz) * nn + zz * hprev;
                }
                hp[jh] = hv;
                union { unsigned short us[4]; unsigned long long u; } pk;
                pk.us[0] = f2bf(hv[0]); pk.us[1] = f2bf(hv[1]);
                pk.us[2] = f2bf(hv[2]); pk.us[3] = f2bf(hv[3]);
                const int qp = jh * 2 + (q >> 1);
                store_sc8u(hw + (qp * 16 + l15) * 8 + (q & 1) * 4, pk.u);
                if (t == T_ - 1)
                    *(f32x4*)&out[OUT_MAIN + (size_t)bw * 2 * H_ + j4] = hv;
            }
            asm volatile("s_waitcnt vmcnt(0)" ::: "memory");
            __builtin_amdgcn_sched_barrier(0);
            if (lane == 0)
                __hip_atomic_store(&fh0[FIDX(t, bt, jp, w)], 1, __ATOMIC_RELAXED, __HIP_MEMORY_SCOPE_AGENT);
        } else if (stage == 2) {
            // ================= G1 =================
            f32x4 acc[6];
            #pragma unroll
            for (int i = 0; i < 6; ++i) acc[i] = f32x4{0.f, 0.f, 0.f, 0.f};
            {
                const int* p = nullptr;
                if (lane < 16)                        p = &fh0[FIDX(t, bt, lane, w)];
                else if (t >= 4 && lane == 16)        p = &fh1[FIDX(t - 4, bt, jp, w)];
                pollw(p);
                asm volatile("" ::: "memory");
                __builtin_amdgcn_sched_barrier(0);
            }
            const __hip_bfloat16* tb = h0r + (((size_t)(t & 3) * 32 + b16) * 16) * 512 + lane * 8;
            gather16d<4>(tb, wlds, l15, kg, false, acc);

            __hip_bfloat16* slab = gi1 + (((size_t)(t & 3) * 4 + bt) * 16 + jp) * GISLAB;
            #pragma unroll
            for (int jf = 0; jf < 6; ++jf)
                store_sc8(slab + ((jf * 8 + w) * 64 + lane) * 4, acc[jf]);
            asm volatile("s_waitcnt vmcnt(0)" ::: "memory");
            __builtin_amdgcn_sched_barrier(0);
            if (lane == 0)
                __hip_atomic_store(&fgi1[FIDX(t, bt, jp, w)], 1, __ATOMIC_RELAXED, __HIP_MEMORY_SCOPE_AGENT);
        } else {
            // ================= R1 =================
            f32x4 acc[6];
            #pragma unroll
            for (int i = 0; i < 6; ++i) acc[i] = f32x4{0.f, 0.f, 0.f, 0.f};
            const bool z = is_init[(size_t)bw * T_ + t] != 0;
            {
                const int* p = nullptr;
                if (t > 0 && lane < 16)   p = &fh1[FIDX(t - 1, bt, lane, w)];
                else if (lane == 16)      p = &fgi1[FIDX(t, bt, jp, w)];
                pollw(p);
                asm volatile("" ::: "memory");
                __builtin_amdgcn_sched_barrier(0);
            }
            const __hip_bfloat16* slab = gi1 + (((size_t)(t & 3) * 4 + bt) * 16 + jp) * GISLAB;
            unsigned long long gu[6];
            #pragma unroll
            for (int jf = 0; jf < 6; ++jf)
                gu[jf] = load_sc8(slab + ((jf * 8 + w) * 64 + lane) * 4);

            if (t == 0) {
                const float* hr = h_in + (size_t)bw * 2 * H_ + H_;
                #pragma unroll
                for (int kc = 0; kc < 16; ++kc) {
                    short8 bf = z ? zed : cvt8v(*(const f32x4*)(hr + kc * 32 + kg),
                                                *(const f32x4*)(hr + kc * 32 + kg + 4));
                    chunk6<KP_, 4>(wlds, l15, kg, kc, bf, acc);
                }
            } else {
                const __hip_bfloat16* tb = h1r + (((size_t)((t - 1) & 3) * 32 + b16) * 16) * 512 + lane * 8;
                gather16d<4>(tb, wlds, l15, kg, z, acc);
            }

            __hip_bfloat16* hw = h1r + (((size_t)(t & 3) * 32 + b16) * 16 + jp) * 512;
            #pragma unroll
            for (int jh = 0; jh < 2; ++jh) {
                const int j4 = jb + jh * 16 + qr4;
                const f32x4 giR = unpk(gu[jh]);
                const f32x4 giZ = unpk(gu[2 + jh]);
                const f32x4 giN = unpk(gu[4 + jh]);
                f32x4 hv;
                #pragma unroll
                for (int r = 0; r < 4; ++r) {
                    const float rr = sigm(giR[r] + acc[jh][r] + bR[jh][r]);
                    const float zz = sigm(giZ[r] + acc[2 + jh][r] + bZ[jh][r]);
                    const float nn = tanhf(giN[r] + bIN[jh][r] + rr * (acc[4 + jh][r] + bHN[jh][r]));
                    const float hprev = z ? 0.0f : hp[jh][r];
                    hv[r] = (1.0f - zz) * nn + zz * hprev;
                }
                hp[jh] = hv;
                union { unsigned short us[4]; unsigned long long u; } pk;
                pk.us[0] = f2bf(hv[0]); pk.us[1] = f2bf(hv[1]);
                pk.us[2] = f2bf(hv[2]); pk.us[3] = f2bf(hv[3]);
                const int qp = jh * 2 + (q >> 1);
                store_sc8u(hw + (qp * 16 + l15) * 8 + (q & 1) * 4, pk.u);
                *(f32x4*)&out[((size_t)bw * T_ + t) * H_ + j4] = hv;
                if (t == T_ - 1)
                    *(f32x4*)&out[OUT_MAIN + (size_t)bw * 2 * H_ + H_ + j4] = hv;
            }
            asm volatile("s_waitcnt vmcnt(0)" ::: "memory");
            __builtin_amdgcn_sched_barrier(0);
            if (lane == 0)
                __hip_atomic_store(&fh1[FIDX(t, bt, jp, w)], 1, __ATOMIC_RELAXED, __HIP_MEMORY_SCOPE_AGENT);
        }
    }
}

extern "C" void kernel_launch(void* const* d_in, const int* in_sizes, int n_in,
                              void* d_out, int out_size, void* d_ws, size_t ws_size,
                              hipStream_t stream) {
    (void)in_sizes; (void)n_in; (void)out_size; (void)ws_size;
    const float* x    = (const float*)d_in[0];
    const int*   isin = (const int*)d_in[1];
    const float* h_in = (const float*)d_in[2];
    const float* wih0 = (const float*)d_in[3];
    const float* whh0 = (const float*)d_in[4];
    const float* bih0 = (const float*)d_in[5];
    const float* bhh0 = (const float*)d_in[6];
    const float* wih1 = (const float*)d_in[7];
    const float* whh1 = (const float*)d_in[8];
    const float* bih1 = (const float*)d_in[9];
    const float* bhh1 = (const float*)d_in[10];
    float* out = (float*)d_out;
    char* ws = (char*)d_ws;

    init_kernel<<<dim3(256), dim3(256), 0, stream>>>((int*)(ws + OFF_FLG));

    gru_wave<<<dim3(256), dim3(512), 0, stream>>>(
        x, isin, h_in,
        wih0, whh0, bih0, bhh0,
        wih1, whh1, bih1, bhh1,
        ws, out);
}

// Round 18
// 1351.305 us; speedup vs baseline: 1.3273x; 1.0013x over previous
//
#include <hip/hip_runtime.h>
#include <hip/hip_bf16.h>

#define B_ 512
#define T_ 128
#define DIN_ 256
#define H_ 512
#define KP_ 520             // LDS stride (bf16) K=512 weights
#define KP0_ 264            // LDS stride K=256 (wih0)
#define OUT_MAIN ((size_t)B_ * T_ * H_)
#define GISLAB 12288

// ws byte offsets
#define OFF_H1  2097152ull
#define OFF_GI1 4194304ull
#define OFF_FLG 16777216ull

typedef __attribute__((ext_vector_type(8))) short short8;
typedef __attribute__((ext_vector_type(4))) float f32x4;

__device__ __forceinline__ float sigm(float v) { return 1.0f / (1.0f + __expf(-v)); }

__device__ __forceinline__ unsigned short f2bf(float f) {
    union { __hip_bfloat16 b; unsigned short u; } c;
    c.b = __float2bfloat16(f);
    return c.u;
}

__device__ __forceinline__ short8 cvt8v(f32x4 u, f32x4 v) {
    short8 o;
    o[0] = (short)f2bf(u[0]); o[1] = (short)f2bf(u[1]);
    o[2] = (short)f2bf(u[2]); o[3] = (short)f2bf(u[3]);
    o[4] = (short)f2bf(v[0]); o[5] = (short)f2bf(v[1]);
    o[6] = (short)f2bf(v[2]); o[7] = (short)f2bf(v[3]);
    return o;
}

// coherent-point (sc0 sc1) 16B load — the proven cross-XCD transport
__device__ __forceinline__ short8 ldh(const __hip_bfloat16* p) {
    short8 r;
    asm volatile("global_load_dwordx4 %0, %1, off sc0 sc1" : "=v"(r) : "v"(p));
    return r;
}
#define VMWAIT(N) do { asm volatile("s_waitcnt vmcnt(" #N ")" ::: "memory"); \
                       __builtin_amdgcn_sched_barrier(0); } while (0)

__device__ __forceinline__ unsigned long long load_sc8(const __hip_bfloat16* p) {
    return __hip_atomic_load((const unsigned long long*)p, __ATOMIC_RELAXED, __HIP_MEMORY_SCOPE_AGENT);
}
__device__ __forceinline__ void store_sc8u(__hip_bfloat16* p, unsigned long long v) {
    __hip_atomic_store((unsigned long long*)p, v, __ATOMIC_RELAXED, __HIP_MEMORY_SCOPE_AGENT);
}
__device__ __forceinline__ void store_sc8(__hip_bfloat16* p, f32x4 h4) {
    union { unsigned short s[4]; unsigned long long u; } r;
    r.s[0] = f2bf(h4[0]); r.s[1] = f2bf(h4[1]);
    r.s[2] = f2bf(h4[2]); r.s[3] = f2bf(h4[3]);
    store_sc8u(p, r.u);
}

__device__ __forceinline__ f32x4 unpk(unsigned long long u) {
    f32x4 r;
    r[0] = __uint_as_float((unsigned)(u & 0xffffull) << 16);
    r[1] = __uint_as_float((unsigned)((u >> 16) & 0xffffull) << 16);
    r[2] = __uint_as_float((unsigned)((u >> 32) & 0xffffull) << 16);
    r[3] = __uint_as_float((unsigned)((u >> 48) & 0xffffull) << 16);
    return r;
}

// divergent per-lane poll on an agent flag (nullptr = no wait)
__device__ __forceinline__ void pollw(const int* p) {
    if (p)
        while (__hip_atomic_load(p, __ATOMIC_RELAXED, __HIP_MEMORY_SCOPE_AGENT) == 0)
            __builtin_amdgcn_s_sleep(1);
}

#define FIDX(t, bt, jp, w) (((((t) * 4 + (bt)) * 16 + (jp)) * 8) + (w))

__global__ void init_kernel(int* __restrict__ flg)
{
    int i = blockIdx.x * blockDim.x + threadIdx.x;
    int stride = gridDim.x * blockDim.x;
    for (int k = i; k < 196608; k += stride)
        __hip_atomic_store(&flg[k], 0, __ATOMIC_RELAXED, __HIP_MEMORY_SCOPE_AGENT);
}

// acc: 0,1 = r ; 2,3 = z ; NB,NB+1 = n
template<int KP, int NB>
__device__ __forceinline__ void chunk6(const __hip_bfloat16* wl, int l15, int kg, int kc,
                                       short8 bf, f32x4* acc) {
    #pragma unroll
    for (int g = 0; g < 3; ++g) {
        const int ai = (g == 2) ? NB : g * 2;
        #pragma unroll
        for (int jh = 0; jh < 2; ++jh) {
            short8 wf = *(const short8*)&wl[(size_t)(g * 32 + jh * 16 + l15) * KP + kc * 32 + kg];
            acc[ai + jh] = __builtin_amdgcn_mfma_f32_16x16x32_bf16(wf, bf, acc[ai + jh], 0, 0, 0);
        }
    }
}

// 16-deep pipelined gather of 16 x 1KB tiles (issue all, counted drains)
template<int NB>
__device__ __forceinline__ void gather16d(const __hip_bfloat16* tb, const __hip_bfloat16* wl,
                                          int l15, int kg, bool z, f32x4* acc)
{
    const short8 zed = {0,0,0,0,0,0,0,0};
    VMWAIT(0);   // honest vmcnt baseline (drains prior flag/out/slab ops)
    short8 v[16];
    #pragma unroll
    for (int i = 0; i < 16; ++i) v[i] = ldh(tb + i * 512);
    VMWAIT(12);
    #pragma unroll
    for (int i = 0; i < 4; ++i)  chunk6<KP_, NB>(wl, l15, kg, i, z ? zed : v[i], acc);
    VMWAIT(8);
    #pragma unroll
    for (int i = 4; i < 8; ++i)  chunk6<KP_, NB>(wl, l15, kg, i, z ? zed : v[i], acc);
    VMWAIT(4);
    #pragma unroll
    for (int i = 8; i < 12; ++i) chunk6<KP_, NB>(wl, l15, kg, i, z ? zed : v[i], acc);
    VMWAIT(0);
    #pragma unroll
    for (int i = 12; i < 16; ++i) chunk6<KP_, NB>(wl, l15, kg, i, z ? zed : v[i], acc);
}

// 256 blocks x 512 threads, stage = bid>>6: 0=R0 (gi0 local + gh0 + fuse -> h0),
// 1=R1 (gh1 + gi1 slab + fuse -> out), 2=G1 (gi1 = h0 @ wih1^T), 3=exit.
// bt=(bid>>4)&3, jp=bid&15. 8 waves = 8 disjoint 16-row groups; ALL dataflow is
// per-wave (flags [t][bt][jp][w]); no __syncthreads in the t-loop.
// R18: R1 issues h1-stores FIRST, out-stores after, then VMWAIT(2) — the drain
// covers only the h1 stores (what consumers need); out-stores ride into the next
// step's gather-start drain, which overlaps the poll window.
__global__ __launch_bounds__(512) void gru_wave(
    const float* __restrict__ x, const int* __restrict__ is_init,
    const float* __restrict__ h_in,
    const float* __restrict__ wih0, const float* __restrict__ whh0,
    const float* __restrict__ bih0, const float* __restrict__ bhh0,
    const float* __restrict__ wih1, const float* __restrict__ whh1,
    const float* __restrict__ bih1, const float* __restrict__ bhh1,
    char* __restrict__ ws, float* __restrict__ out)
{
    __shared__ __hip_bfloat16 wsh[96 * KP_ + 96 * KP0_];   // 150528 B

    const int bid = blockIdx.x;
    const int stage = bid >> 6;
    if (stage == 3) return;
    const int bt = (bid >> 4) & 3;
    const int jp = bid & 15;

    __hip_bfloat16* h0r = (__hip_bfloat16*)ws;                 // [4][32][16][512]
    __hip_bfloat16* h1r = (__hip_bfloat16*)(ws + OFF_H1);
    __hip_bfloat16* gi1 = (__hip_bfloat16*)(ws + OFF_GI1);     // [4][4][16][12288]
    int* flg  = (int*)(ws + OFF_FLG);
    int* fh0  = flg;
    int* fh1  = flg + 65536;
    int* fgi1 = flg + 131072;

    const int tid = threadIdx.x;
    const int lane = tid & 63;
    const int w = tid >> 6;
    const int l15 = lane & 15;
    const int q = lane >> 4;
    const int kg = q * 8;
    const int qr4 = q * 4;
    const int rb = bt * 128;
    const int jb = jp * 32;
    const int bw = rb + w * 16 + l15;
    const int b16 = bt * 8 + w;

    // ---- stage weights into LDS (f32 -> bf16), once ----
    __hip_bfloat16* wlds  = wsh;
    __hip_bfloat16* wlds2 = wsh + 96 * KP_;
    {
        const float* Wsrc = (stage == 0) ? whh0 : (stage == 1) ? whh1 : wih1;
        for (int idx = tid; idx < 96 * 64; idx += 512) {
            int gr = idx >> 6, c8 = idx & 63;
            int grow = (gr >> 5) * H_ + jb + (gr & 31);
            const float* p = Wsrc + (size_t)grow * H_ + c8 * 8;
            *(short8*)&wlds[(size_t)gr * KP_ + c8 * 8] = cvt8v(*(const f32x4*)p, *(const f32x4*)(p + 4));
        }
        if (stage == 0) {
            for (int idx = tid; idx < 96 * 32; idx += 512) {
                int gr = idx >> 5, c8 = idx & 31;
                int grow = (gr >> 5) * H_ + jb + (gr & 31);
                const float* p = wih0 + (size_t)grow * DIN_ + c8 * 8;
                *(short8*)&wlds2[(size_t)gr * KP0_ + c8 * 8] = cvt8v(*(const f32x4*)p, *(const f32x4*)(p + 4));
            }
        }
    }

    // ---- per-lane constants for R stages ----
    f32x4 bR[2], bZ[2], bIN[2], bHN[2], hp[2];
    if (stage < 2) {
        const float* bi = stage ? bih1 : bih0;
        const float* bh = stage ? bhh1 : bhh0;
        #pragma unroll
        for (int jh = 0; jh < 2; ++jh) {
            const int j4 = jb + jh * 16 + qr4;
            bR[jh]  = *(const f32x4*)&bi[j4]          + *(const f32x4*)&bh[j4];
            bZ[jh]  = *(const f32x4*)&bi[H_ + j4]     + *(const f32x4*)&bh[H_ + j4];
            bIN[jh] = *(const f32x4*)&bi[2 * H_ + j4];
            bHN[jh] = *(const f32x4*)&bh[2 * H_ + j4];
            hp[jh]  = *(const f32x4*)&h_in[(size_t)bw * 2 * H_ + (size_t)stage * H_ + j4];
        }
    }
    __syncthreads();   // LDS weights ready; last sync — waves free-run from here

    const short8 zed = {0, 0, 0, 0, 0, 0, 0, 0};

    for (int t = 0; t < T_; ++t) {
        if (stage == 0) {
            // ================= R0 =================
            f32x4 acc[8];
            #pragma unroll
            for (int i = 0; i < 8; ++i) acc[i] = f32x4{0.f, 0.f, 0.f, 0.f};
            const bool z = is_init[(size_t)bw * T_ + t] != 0;

            // gi0 = x @ wih0^T (independent -> before polls)
            const float* xr = x + ((size_t)bw * T_ + t) * DIN_;
            #pragma unroll
            for (int kc = 0; kc < 8; ++kc) {
                short8 bf = cvt8v(*(const f32x4*)(xr + kc * 32 + kg),
                                  *(const f32x4*)(xr + kc * 32 + kg + 4));
                chunk6<KP0_, 4>(wlds2, l15, kg, kc, bf, acc);
            }

            // per-wave dataflow waits
            {
                const int* p = nullptr;
                if (t > 0 && lane < 16)                       p = &fh0[FIDX(t - 1, bt, lane, w)];
                else if (t >= 4 && lane >= 32 && lane < 48)   p = &fgi1[FIDX(t - 4, bt, lane - 32, w)];
                pollw(p);
                asm volatile("" ::: "memory");
                __builtin_amdgcn_sched_barrier(0);
            }

            // gh0 over h0[t-1]
            if (t == 0) {
                const float* hr = h_in + (size_t)bw * 2 * H_;
                #pragma unroll
                for (int kc = 0; kc < 16; ++kc) {
                    short8 bf = z ? zed : cvt8v(*(const f32x4*)(hr + kc * 32 + kg),
                                                *(const f32x4*)(hr + kc * 32 + kg + 4));
                    chunk6<KP_, 6>(wlds, l15, kg, kc, bf, acc);
                }
            } else {
                const __hip_bfloat16* tb = h0r + (((size_t)((t - 1) & 3) * 32 + b16) * 16) * 512 + lane * 8;
                gather16d<6>(tb, wlds, l15, kg, z, acc);
            }

            // fuse + publish h0[t] (per-wave)
            __hip_bfloat16* hw = h0r + (((size_t)(t & 3) * 32 + b16) * 16 + jp) * 512;
            #pragma unroll
            for (int jh = 0; jh < 2; ++jh) {
                const int j4 = jb + jh * 16 + qr4;
                f32x4 hv;
                #pragma unroll
                for (int r = 0; r < 4; ++r) {
                    const float rr = sigm(acc[jh][r] + bR[jh][r]);
                    const float zz = sigm(acc[2 + jh][r] + bZ[jh][r]);
                    const float nn = tanhf(acc[4 + jh][r] + bIN[jh][r] + rr * (acc[6 + jh][r] + bHN[jh][r]));
                    const float hprev = z ? 0.0f : hp[jh][r];
                    hv[r] = (1.0f - zz) * nn + zz * hprev;
                }
                hp[jh] = hv;
                union { unsigned short us[4]; unsigned long long u; } pk;
                pk.us[0] = f2bf(hv[0]); pk.us[1] = f2bf(hv[1]);
                pk.us[2] = f2bf(hv[2]); pk.us[3] = f2bf(hv[3]);
                const int qp = jh * 2 + (q >> 1);
                store_sc8u(hw + (qp * 16 + l15) * 8 + (q & 1) * 4, pk.u);
                if (t == T_ - 1)
                    *(f32x4*)&out[OUT_MAIN + (size_t)bw * 2 * H_ + j4] = hv;
            }
            asm volatile("s_waitcnt vmcnt(0)" ::: "memory");
            __builtin_amdgcn_sched_barrier(0);
            if (lane == 0)
                __hip_atomic_store(&fh0[FIDX(t, bt, jp, w)], 1, __ATOMIC_RELAXED, __HIP_MEMORY_SCOPE_AGENT);
        } else if (stage == 2) {
            // ================= G1 =================
            f32x4 acc[6];
            #pragma unroll
            for (int i = 0; i < 6; ++i) acc[i] = f32x4{0.f, 0.f, 0.f, 0.f};
            {
                const int* p = nullptr;
                if (lane < 16)                        p = &fh0[FIDX(t, bt, lane, w)];
                else if (t >= 4 && lane == 16)        p = &fh1[FIDX(t - 4, bt, jp, w)];
                pollw(p);
                asm volatile("" ::: "memory");
                __builtin_amdgcn_sched_barrier(0);
            }
            const __hip_bfloat16* tb = h0r + (((size_t)(t & 3) * 32 + b16) * 16) * 512 + lane * 8;
            gather16d<4>(tb, wlds, l15, kg, false, acc);

            __hip_bfloat16* slab = gi1 + (((size_t)(t & 3) * 4 + bt) * 16 + jp) * GISLAB;
            #pragma unroll
            for (int jf = 0; jf < 6; ++jf)
                store_sc8(slab + ((jf * 8 + w) * 64 + lane) * 4, acc[jf]);
            asm volatile("s_waitcnt vmcnt(0)" ::: "memory");
            __builtin_amdgcn_sched_barrier(0);
            if (lane == 0)
                __hip_atomic_store(&fgi1[FIDX(t, bt, jp, w)], 1, __ATOMIC_RELAXED, __HIP_MEMORY_SCOPE_AGENT);
        } else {
            // ================= R1 =================
            f32x4 acc[6];
            #pragma unroll
            for (int i = 0; i < 6; ++i) acc[i] = f32x4{0.f, 0.f, 0.f, 0.f};
            const bool z = is_init[(size_t)bw * T_ + t] != 0;
            {
                const int* p = nullptr;
                if (t > 0 && lane < 16)   p = &fh1[FIDX(t - 1, bt, lane, w)];
                else if (lane == 16)      p = &fgi1[FIDX(t, bt, jp, w)];
                pollw(p);
                asm volatile("" ::: "memory");
                __builtin_amdgcn_sched_barrier(0);
            }
            const __hip_bfloat16* slab = gi1 + (((size_t)(t & 3) * 4 + bt) * 16 + jp) * GISLAB;
            unsigned long long gu[6];
            #pragma unroll
            for (int jf = 0; jf < 6; ++jf)
                gu[jf] = load_sc8(slab + ((jf * 8 + w) * 64 + lane) * 4);

            if (t == 0) {
                const float* hr = h_in + (size_t)bw * 2 * H_ + H_;
                #pragma unroll
                for (int kc = 0; kc < 16; ++kc) {
                    short8 bf = z ? zed : cvt8v(*(const f32x4*)(hr + kc * 32 + kg),
                                                *(const f32x4*)(hr + kc * 32 + kg + 4));
                    chunk6<KP_, 4>(wlds, l15, kg, kc, bf, acc);
                }
            } else {
                const __hip_bfloat16* tb = h1r + (((size_t)((t - 1) & 3) * 32 + b16) * 16) * 512 + lane * 8;
                gather16d<4>(tb, wlds, l15, kg, z, acc);
            }

            // ---- fuse; h1 stores FIRST, out stores after (drain excludes them) ----
            __hip_bfloat16* hw = h1r + (((size_t)(t & 3) * 32 + b16) * 16 + jp) * 512;
            f32x4 hv2[2];
            unsigned long long pku[2];
            #pragma unroll
            for (int jh = 0; jh < 2; ++jh) {
                const f32x4 giR = unpk(gu[jh]);
                const f32x4 giZ = unpk(gu[2 + jh]);
                const f32x4 giN = unpk(gu[4 + jh]);
                f32x4 hv;
                #pragma unroll
                for (int r = 0; r < 4; ++r) {
                    const float rr = sigm(giR[r] + acc[jh][r] + bR[jh][r]);
                    const float zz = sigm(giZ[r] + acc[2 + jh][r] + bZ[jh][r]);
                    const float nn = tanhf(giN[r] + bIN[jh][r] + rr * (acc[4 + jh][r] + bHN[jh][r]));
                    const float hprev = z ? 0.0f : hp[jh][r];
                    hv[r] = (1.0f - zz) * nn + zz * hprev;
                }
                hp[jh] = hv;
                hv2[jh] = hv;
                union { unsigned short us[4]; unsigned long long u; } pk;
                pk.us[0] = f2bf(hv[0]); pk.us[1] = f2bf(hv[1]);
                pk.us[2] = f2bf(hv[2]); pk.us[3] = f2bf(hv[3]);
                pku[jh] = pk.u;
            }
            #pragma unroll
            for (int jh = 0; jh < 2; ++jh) {
                const int qp = jh * 2 + (q >> 1);
                store_sc8u(hw + (qp * 16 + l15) * 8 + (q & 1) * 4, pku[jh]);
            }
            #pragma unroll
            for (int jh = 0; jh < 2; ++jh) {
                const int j4 = jb + jh * 16 + qr4;
                *(f32x4*)&out[((size_t)bw * T_ + t) * H_ + j4] = hv2[jh];
            }
            if (t == T_ - 1) {
                #pragma unroll
                for (int jh = 0; jh < 2; ++jh) {
                    const int j4 = jb + jh * 16 + qr4;
                    *(f32x4*)&out[OUT_MAIN + (size_t)bw * 2 * H_ + H_ + j4] = hv2[jh];
                }
                VMWAIT(0);
            } else {
                VMWAIT(2);   // drains the 2 h1 stores; 2 out stores stay in flight
            }
            if (lane == 0)
                __hip_atomic_store(&fh1[FIDX(t, bt, jp, w)], 1, __ATOMIC_RELAXED, __HIP_MEMORY_SCOPE_AGENT);
        }
    }
}

extern "C" void kernel_launch(void* const* d_in, const int* in_sizes, int n_in,
                              void* d_out, int out_size, void* d_ws, size_t ws_size,
                              hipStream_t stream) {
    (void)in_sizes; (void)n_in; (void)out_size; (void)ws_size;
    const float* x    = (const float*)d_in[0];
    const int*   isin = (const int*)d_in[1];
    const float* h_in = (const float*)d_in[2];
    const float* wih0 = (const float*)d_in[3];
    const float* whh0 = (const float*)d_in[4];
    const float* bih0 = (const float*)d_in[5];
    const float* bhh0 = (const float*)d_in[6];
    const float* wih1 = (const float*)d_in[7];
    const float* whh1 = (const float*)d_in[8];
    const float* bih1 = (const float*)d_in[9];
    const float* bhh1 = (const float*)d_in[10];
    float* out = (float*)d_out;
    char* ws = (char*)d_ws;

    init_kernel<<<dim3(256), dim3(256), 0, stream>>>((int*)(ws + OFF_FLG));

    gru_wave<<<dim3(256), dim3(512), 0, stream>>>(
        x, isin, h_in,
        wih0, whh0, bih0, bhh0,
        wih1, whh1, bih1, bhh1,
        ws, out);
}